// Round 1
// baseline (152.462 us; speedup 1.0000x reference)
//
#include <hip/hip_runtime.h>

#define LL   8192   // sequence length
#define CC   2048   // channels
#define FF   128    // inner dim of g@kernel
#define KK   257    // taps
#define PAD  128    // (KK-1)/2

#define SROWP 328   // PADDED synEb row stride (u16): 32 zeros | 257 taps | 31 zeros | 8 zero pad
#define NT   18     // K-steps of 16 -> covers K in [0,288)

#define ROWS 1280   // xch LDS row in ushorts (2560 B, %16==0). 16 rows = 40,960 B
                    // -> 4 blocks/CU exactly (4 x 40,960 = 160 KiB), grid 1024 = 4 x 256 CUs: zero tail.

typedef __bf16 bf16x8 __attribute__((ext_vector_type(8)));
typedef float  f32x16 __attribute__((ext_vector_type(16)));

static __device__ __forceinline__ unsigned short f2bf(float f) {
    unsigned u = __float_as_uint(f);
    u = (u + 0x7fffu + ((u >> 16) & 1u)) >> 16;   // RNE
    return (unsigned short)u;
}

// Build synEb[c][328] bf16: zeros | g[c,:]@kernel[:,k] | zeros (incl. 8-u16 zero pad),
// with the Yt-row override folded in as a delta kernel (tap=1 at k=128) so the conv
// reproduces out[c,l] = x[l,c] exactly for flagged channels.
__global__ __launch_bounds__(256) void synb_kernel(const float* __restrict__ g,
                                                   const float* __restrict__ kern,
                                                   const int* __restrict__ Yt, int ny,
                                                   unsigned short* __restrict__ synEb) {
    __shared__ int sfl[4];
    const int c0 = blockIdx.x * 4;
    const int t  = threadIdx.x;
    if (t < 4) sfl[t] = 0;
    __syncthreads();
    for (int i = t; i < ny; i += 256) {
        int y = Yt[i];
        #pragma unroll
        for (int ii = 0; ii < 4; ++ii) if (y == c0 + ii) sfl[ii] = 1;
    }
    __syncthreads();
    const float* g0 = g + (size_t)(c0 + 0) * FF;
    const float* g1 = g + (size_t)(c0 + 1) * FF;
    const float* g2 = g + (size_t)(c0 + 2) * FF;
    const float* g3 = g + (size_t)(c0 + 3) * FF;
    const int fl0 = sfl[0], fl1 = sfl[1], fl2 = sfl[2], fl3 = sfl[3];
    for (int p = t; p < SROWP; p += 256) {
        const int kk = p - 32;
        float a0 = 0.f, a1 = 0.f, a2 = 0.f, a3 = 0.f;
        const bool inr = (kk >= 0) && (kk < KK);
        if (inr) {
            #pragma unroll 8
            for (int f = 0; f < FF; ++f) {
                float kv = kern[f * KK + kk];      // coalesced across p
                a0 += kv * g0[f];
                a1 += kv * g1[f];
                a2 += kv * g2[f];
                a3 += kv * g3[f];
            }
        }
        float dlt = (kk == PAD) ? 1.f : 0.f;
        float v0 = inr ? (fl0 ? dlt : a0) : 0.f;
        float v1 = inr ? (fl1 ? dlt : a1) : 0.f;
        float v2 = inr ? (fl2 ? dlt : a2) : 0.f;
        float v3 = inr ? (fl3 ? dlt : a3) : 0.f;
        synEb[(size_t)(c0 + 0) * SROWP + p] = f2bf(v0);
        synEb[(size_t)(c0 + 1) * SROWP + p] = f2bf(v1);
        synEb[(size_t)(c0 + 2) * SROWP + p] = f2bf(v2);
        synEb[(size_t)(c0 + 3) * SROWP + p] = f2bf(v3);
    }
}

// Fused transpose + depthwise Toeplitz-MFMA conv.
// Block: 16 channels x 1024 outputs. Stage x[(L,C) fp32] -> LDS bf16 rows
// (XOR-granule-swizzled), one barrier, then each wave MFMAs 4 channels
// (18 x mfma_f32_32x32x16_bf16 each). B-fragments are read directly from
// global synEb (1.34 MB, L2-resident; per-instr span <= 2 cache lines) --
// no synL LDS buffer, so 4 blocks/CU fit exactly and the 1024-block grid
// dispatches in ONE full round (no tail).
__global__ __launch_bounds__(256, 4) void fused_conv(const float* __restrict__ x,
                                                     const unsigned short* __restrict__ synEb,
                                                     float* __restrict__ out) {
    __shared__ alignas(16) unsigned short xch[16][ROWS];   // 40,960 B exactly
    const int t  = threadIdx.x;
    const int W0 = blockIdx.x << 10;          // window base (l of output 0)
    const int c0 = blockIdx.y << 4;

    // ---- stage x window: logical p in [0,1280), xpad[p] = x[W0+p-128][c] ----
    #pragma unroll
    for (int k = 0; k < 10; ++k) {
        int pidx = (k << 8) + t;              // [0,2560)
        int ch4  = pidx & 3;                  // float4 channel quad
        int pp   = pidx >> 2;                 // dword (l-pair) index [0,640)
        int lg   = W0 + (pp << 1) - 128;      // global l of even element
        const float* sp = x + (size_t)lg * CC + c0 + (ch4 << 2);
        float4 ve = make_float4(0.f, 0.f, 0.f, 0.f);
        float4 vo = make_float4(0.f, 0.f, 0.f, 0.f);
        if ((unsigned)lg       < (unsigned)LL) ve = *(const float4*)sp;        // 16 segs/instr
        if ((unsigned)(lg + 1) < (unsigned)LL) vo = *(const float4*)(sp + CC);
        int gq = pp >> 2;                     // granule (8 u16)
        int gp = gq ^ ((gq >> 3) & 7);        // XOR swizzle (R2-verified)
        int dw = (gp << 2) | (pp & 3);        // dword slot within row [0,640)
        const float* pe = (const float*)&ve;
        const float* po = (const float*)&vo;
        #pragma unroll
        for (int c2 = 0; c2 < 4; ++c2) {
            unsigned val = (unsigned)f2bf(pe[c2]) | ((unsigned)f2bf(po[c2]) << 16);
            ((unsigned*)xch[(ch4 << 2) + c2])[dw] = val;
        }
    }
    __syncthreads();

    const int w = t >> 6, ln = t & 63;
    const int j = ln & 31, q = ln >> 5;
    const int bb  = (q << 4) - 2 * j + 64;    // byte base of bfrag m=0 (in [2,80], even)
    const int dwb = bb >> 2;                  // dword base at m=0 (in [0,20])
    const int sh  = (bb & 2) << 3;            // residual funnel shift: 0 or 16 bits
    const int gb  = (j << 2) + q;             // A granule base

    for (int cc = 0; cc < 4; ++cc) {
        const int ci = (w << 2) + cc;
        // B source: global synEb row (padded to 164 dwords; w4 read at m=17
        // reaches dword index dwb+140 <= 160 < 164 -> always in-allocation,
        // pad is written zero by synb_kernel).
        const unsigned* rp = (const unsigned*)(synEb + (size_t)(c0 + ci) * SROWP) + dwb;
        f32x16 acc;
        #pragma unroll
        for (int r = 0; r < 16; ++r) acc[r] = 0.f;
        // ---- fused per-m: 5 global dword loads (one addr reg + imm offsets),
        //      4 funnel shifts (v_alignbit), 1 ds_read_b128, 1 MFMA ----
        #pragma unroll
        for (int m = 0; m < NT; ++m) {
            unsigned w0 = rp[(m << 3) + 0], w1 = rp[(m << 3) + 1], w2 = rp[(m << 3) + 2],
                     w3 = rp[(m << 3) + 3], w4 = rp[(m << 3) + 4];
            union { unsigned d[4]; bf16x8 v; } B;
            B.d[0] = (unsigned)((((unsigned long long)w1 << 32) | w0) >> sh);
            B.d[1] = (unsigned)((((unsigned long long)w2 << 32) | w1) >> sh);
            B.d[2] = (unsigned)((((unsigned long long)w3 << 32) | w2) >> sh);
            B.d[3] = (unsigned)((((unsigned long long)w4 << 32) | w3) >> sh);
            int gq = gb + (m << 1);
            int gp = gq ^ ((gq >> 3) & 7);
            union { int4 i4; bf16x8 v; } A;
            A.i4 = *(const int4*)(&xch[ci][gp << 3]);
            acc = __builtin_amdgcn_mfma_f32_32x32x16_bf16(A.v, B.v, acc, 0, 0, 0);
        }
        // ---- store: D col=lane&31, row=(r&3)+8*(r>>2)+4q ----
        float* o = out + (size_t)(c0 + ci) * LL + W0 + j;
        #pragma unroll
        for (int r = 0; r < 16; ++r) {
            int row = (r & 3) + ((r >> 2) << 3) + (q << 2);
            o[row << 5] = acc[r];             // 2 x 128B segments per instr
        }
    }
}

// ------------------------------------------------------------------- launch
extern "C" void kernel_launch(void* const* d_in, const int* in_sizes, int n_in,
                              void* d_out, int out_size, void* d_ws, size_t ws_size,
                              hipStream_t stream) {
    const float* x    = (const float*)d_in[0];
    const int*   Yt   = (const int*)  d_in[1];
    const float* g    = (const float*)d_in[2];
    const float* kern = (const float*)d_in[3];
    float* out = (float*)d_out;
    const int ny = in_sizes[1];

    unsigned short* synEb = (unsigned short*)d_ws;   // 2048*328*2 = 1.34 MB

    synb_kernel<<<CC / 4, 256, 0, stream>>>(g, kern, Yt, ny, synEb);
    fused_conv<<<dim3(LL / 1024, CC / 16), 256, 0, stream>>>(x, synEb, out);
}